// Round 6
// baseline (296.481 us; speedup 1.0000x reference)
//
#include <hip/hip_runtime.h>
#include <math.h>

// TensorSketch degree-3: out[b] = irfft( prod_d rfft(countsketch_d(X[b])) )
// B=8192, F=4096, N=512.
//
// R6: zero-barrier wave-private design. Each 64-lane wave owns one row pair
// end-to-end. Features split into 4 quarters of 1024; CSR built per
// (degree, quarter): entries sorted by bucket, value = f_local | bit<<15.
// Wave loop per quarter: stage own pair's quarter into an 8 KB wave-private
// LDS slice (coalesced float4), gather entries straight into z[3][8]
// accumulator REGISTERS (no exch buffer, no handoff, NO __syncthreads in the
// whole kernel). Then register-resident FFT-512 (pair packed as real/imag):
// DIF fwd (3 reg stages + 6 shfl_xor lane stages, twiddles hoisted to regs),
// conj-partner extraction via shfl, spectral product, DIT inverse, store.
// LDS = 4 waves x 8 KB = 32 KB.

#define F_DIM 4096
#define NC 512
#define DEG 3
#define THREADS 256
#define PI_F 3.14159265358979323846f

#define NQ 4                       // feature quarters
#define QF (F_DIM / NQ)            // 1024 features per quarter
#define OFSQ_STRIDE 513            // ushorts per (d,q) offsets row
#define ENT_BYTE_OFF 16384         // entries start at ws + 16 KB

__device__ __forceinline__ float2 cmul(float2 a, float2 b) {
    return make_float2(a.x * b.x - a.y * b.y, a.x * b.y + a.y * b.x);
}
__device__ __forceinline__ float2 cmulc(float2 a, float2 b) {   // a * conj(b)
    return make_float2(a.x * b.x + a.y * b.y, a.y * b.x - a.x * b.y);
}
__device__ __forceinline__ float2 shflx(float2 v, int m) {
    return make_float2(__shfl_xor(v.x, m), __shfl_xor(v.y, m));
}

// DIF lane-stage: lower: a+b ; upper: (a-b)*w
__device__ __forceinline__ void fwd_lane_stage(float2 (&s)[8], int lane, int m, float2 w) {
    const bool up = (lane & m) != 0;
    const float sg = up ? -1.0f : 1.0f;
    const float2 weff = up ? w : make_float2(1.0f, 0.0f);
    #pragma unroll
    for (int r = 0; r < 8; ++r) {
        const float2 zz = s[r];
        const float2 pp = shflx(zz, m);
        const float2 dd = make_float2(fmaf(sg, zz.x, pp.x), fmaf(sg, zz.y, pp.y));
        s[r] = cmul(dd, weff);
    }
}
// DIT lane-stage: t = b*conj(w); lower: a+t ; upper: a-t
__device__ __forceinline__ void inv_lane_stage(float2 (&s)[8], int lane, int m, float2 w) {
    const bool up = (lane & m) != 0;
    const float sg = up ? -1.0f : 1.0f;
    #pragma unroll
    for (int r = 0; r < 8; ++r) {
        const float2 zz = s[r];
        const float2 pp = shflx(zz, m);
        const float2 a  = up ? pp : zz;
        const float2 bs = up ? zz : pp;
        const float2 t  = cmulc(bs, w);
        s[r] = make_float2(fmaf(sg, t.x, a.x), fmaf(sg, t.y, a.y));
    }
}

// ---------- kernel 1: build per-(degree,quarter) CSR ----------
// grid = DEG*NQ blocks; block (d,q) sorts its 1024 features by bucket.
__global__ __launch_bounds__(512) void build_csr(
    const int* __restrict__ idxh,
    const int* __restrict__ bith,
    ushort* __restrict__ ofsq_g,   // [DEG*NQ][OFSQ_STRIDE]
    ushort* __restrict__ ent_g)    // [DEG*NQ][QF]
{
    __shared__ unsigned cnt[NC];
    __shared__ unsigned scn[NC];
    const int d = blockIdx.x >> 2;
    const int q = blockIdx.x & 3;
    const int t = threadIdx.x;
    const int fbase = d * F_DIM + q * QF;

    cnt[t] = 0;
    __syncthreads();
    for (int f = t; f < QF; f += 512)
        atomicAdd(&cnt[idxh[fbase + f]], 1u);
    __syncthreads();

    scn[t] = cnt[t];
    __syncthreads();
    for (int off = 1; off < NC; off <<= 1) {
        unsigned v = scn[t];
        if (t >= off) v += scn[t - off];
        __syncthreads();
        scn[t] = v;
        __syncthreads();
    }

    const unsigned excl = t ? scn[t - 1] : 0u;
    ofsq_g[blockIdx.x * OFSQ_STRIDE + t] = (ushort)excl;
    cnt[t] = excl;                        // reuse as placement cursor
    if (t == 0) ofsq_g[blockIdx.x * OFSQ_STRIDE + NC] = (ushort)QF;
    __syncthreads();

    for (int f = t; f < QF; f += 512) {
        const int b = idxh[fbase + f];
        const unsigned pos = atomicAdd(&cnt[b], 1u);
        ent_g[blockIdx.x * QF + pos] = (ushort)(f | (bith[fbase + f] << 15));
    }
}

// ---------- kernel 2: wave-private gather + register FFT ----------
__global__ __launch_bounds__(THREADS, 4) void ts_kernel(
    const float* __restrict__ X,
    const ushort* __restrict__ ofsq_g,
    const ushort* __restrict__ ent_g,
    float* __restrict__ out)
{
    __shared__ float2 xst[4][QF];        // 32 KB total, 8 KB wave-private slices

    const int tid  = threadIdx.x;
    const int lane = tid & 63;
    const int wave = tid >> 6;
    const int pair = blockIdx.x * 4 + wave;
    const int r0   = pair * 2;

    float2* xw = xst[wave];
    float4* xw4 = (float4*)xw;

    // ---- gather accumulators (position n = it*64 + lane) ----
    float2 z[DEG][8];
    #pragma unroll
    for (int d = 0; d < DEG; ++d)
        #pragma unroll
        for (int it = 0; it < 8; ++it)
            z[d][it] = make_float2(0.0f, 0.0f);

    // ---- quarter loop: stage own pair's quarter, gather into registers ----
    for (int q = 0; q < NQ; ++q) {
        const float4* X0q = (const float4*)(X + (size_t)r0 * F_DIM + q * QF);
        const float4* X1q = (const float4*)(X + (size_t)(r0 + 1) * F_DIM + q * QF);
        #pragma unroll
        for (int k = 0; k < 4; ++k) {
            const int i4 = lane + k * 64;            // float4 index within quarter
            const float4 a = X0q[i4];
            const float4 b = X1q[i4];
            xw4[2 * i4]     = make_float4(a.x, b.x, a.y, b.y);
            xw4[2 * i4 + 1] = make_float4(a.z, b.z, a.w, b.w);
        }
        // in-wave ds_write -> ds_read ordering handled by compiler lgkmcnt

        #pragma unroll
        for (int d = 0; d < DEG; ++d) {
            const int blkq = d * NQ + q;
            const ushort* ofs = ofsq_g + blkq * OFSQ_STRIDE;
            const ushort* ep  = ent_g + blkq * QF;
            #pragma unroll
            for (int it = 0; it < 8; ++it) {
                const int b = it * 64 + lane;
                int e = ofs[b];
                const int eend = ofs[b + 1];
                float ax = 0.0f, ay = 0.0f;
                for (; e < eend; ++e) {
                    const ushort u = ep[e];
                    const float2 v = xw[u & 1023];
                    const float s = (u & 0x8000) ? 1.0f : -1.0f;   // bit=1 -> +1
                    ax += s * v.x;
                    ay += s * v.y;
                }
                z[d][it].x += ax;
                z[d][it].y += ay;
            }
        }
    }

    // ---- hoist twiddles: W = exp(-2*pi*i/512) powers, per (stage, lane) ----
    const float wang = -2.0f * PI_F / 512.0f;
    float2 tw0[4], tw1[2], tw2, tw3, tw4, tw5, tw6, tw7;
    #pragma unroll
    for (int c = 0; c < 4; ++c) {
        float sv, cv; __sincosf(wang * (float)(c * 64 + lane), &sv, &cv);
        tw0[c] = make_float2(cv, sv);
    }
    #pragma unroll
    for (int c = 0; c < 2; ++c) {
        float sv, cv; __sincosf(wang * (float)(2 * (c * 64 + lane)), &sv, &cv);
        tw1[c] = make_float2(cv, sv);
    }
    { float sv, cv; __sincosf(wang * (float)(4 * lane),          &sv, &cv); tw2 = make_float2(cv, sv); }
    { float sv, cv; __sincosf(wang * (float)(8 * (lane & 31)),   &sv, &cv); tw3 = make_float2(cv, sv); }
    { float sv, cv; __sincosf(wang * (float)(16 * (lane & 15)),  &sv, &cv); tw4 = make_float2(cv, sv); }
    { float sv, cv; __sincosf(wang * (float)(32 * (lane & 7)),   &sv, &cv); tw5 = make_float2(cv, sv); }
    { float sv, cv; __sincosf(wang * (float)(64 * (lane & 3)),   &sv, &cv); tw6 = make_float2(cv, sv); }
    { float sv, cv; __sincosf(wang * (float)(128 * (lane & 1)),  &sv, &cv); tw7 = make_float2(cv, sv); }

    // conjugate-partner lane for register 0 (bit-rev positions 0..63)
    int jp0 = 0;
    if (lane >= 1) { const int msb = 31 - __builtin_clz((unsigned)lane); jp0 = lane ^ ((1 << msb) - 1); }

    // ---- per degree: forward DIF FFT + extraction + product ----
    float2 P0[8], P1[8];
    #pragma unroll
    for (int it = 0; it < 8; ++it) { P0[it] = make_float2(1.0f, 0.0f); P1[it] = make_float2(1.0f, 0.0f); }

    #pragma unroll
    for (int d = 0; d < DEG; ++d) {
        float2 s[8];
        #pragma unroll
        for (int it = 0; it < 8; ++it) s[it] = z[d][it];

        // stage 0 (h=256): pairs (c, c+4), w = tw0[c]
        #pragma unroll
        for (int c = 0; c < 4; ++c) {
            const float2 a = s[c], b = s[c + 4];
            s[c]     = make_float2(a.x + b.x, a.y + b.y);
            s[c + 4] = cmul(make_float2(a.x - b.x, a.y - b.y), tw0[c]);
        }
        // stage 1 (h=128): pairs (g*4+c, +2), w = tw1[c]
        #pragma unroll
        for (int g = 0; g < 2; ++g)
            #pragma unroll
            for (int c = 0; c < 2; ++c) {
                const int i1 = g * 4 + c, i2 = i1 + 2;
                const float2 a = s[i1], b = s[i2];
                s[i1] = make_float2(a.x + b.x, a.y + b.y);
                s[i2] = cmul(make_float2(a.x - b.x, a.y - b.y), tw1[c]);
            }
        // stage 2 (h=64): pairs (2g, 2g+1), w = tw2
        #pragma unroll
        for (int g = 0; g < 4; ++g) {
            const int i1 = 2 * g, i2 = i1 + 1;
            const float2 a = s[i1], b = s[i2];
            s[i1] = make_float2(a.x + b.x, a.y + b.y);
            s[i2] = cmul(make_float2(a.x - b.x, a.y - b.y), tw2);
        }
        // lane stages (h = 32..1)
        fwd_lane_stage(s, lane, 32, tw3);
        fwd_lane_stage(s, lane, 16, tw4);
        fwd_lane_stage(s, lane, 8,  tw5);
        fwd_lane_stage(s, lane, 4,  tw6);
        fwd_lane_stage(s, lane, 2,  tw7);
        fwd_lane_stage(s, lane, 1,  make_float2(1.0f, 0.0f));

        // extraction partners in bit-rev domain: jp = u ^ (2^msb(u)-1)
        float2 zp[8];
        zp[0] = make_float2(__shfl(s[0].x, jp0), __shfl(s[0].y, jp0));
        zp[1] = shflx(s[1], 63);
        zp[2] = shflx(s[3], 63);
        zp[3] = shflx(s[2], 63);
        zp[4] = shflx(s[7], 63);
        zp[5] = shflx(s[6], 63);
        zp[6] = shflx(s[5], 63);
        zp[7] = shflx(s[4], 63);
        #pragma unroll
        for (int it = 0; it < 8; ++it) {
            const float2 zk = s[it], zq = zp[it];
            const float2 A = make_float2(0.5f * (zk.x + zq.x), 0.5f * (zk.y - zq.y));
            const float2 B = make_float2(0.5f * (zk.y + zq.y), 0.5f * (zq.x - zk.x));
            P0[it] = cmul(P0[it], A);
            P1[it] = cmul(P1[it], B);
        }
    }

    // ---- Q = P0 + i*P1 (bit-rev order), inverse DIT in registers ----
    float2 q2[8];
    #pragma unroll
    for (int it = 0; it < 8; ++it)
        q2[it] = make_float2(P0[it].x - P1[it].y, P0[it].y + P1[it].x);

    inv_lane_stage(q2, lane, 1,  make_float2(1.0f, 0.0f));
    inv_lane_stage(q2, lane, 2,  tw7);
    inv_lane_stage(q2, lane, 4,  tw6);
    inv_lane_stage(q2, lane, 8,  tw5);
    inv_lane_stage(q2, lane, 16, tw4);
    inv_lane_stage(q2, lane, 32, tw3);
    // stage s=6: pairs (2g, 2g+1), w = conj(tw2)
    #pragma unroll
    for (int g = 0; g < 4; ++g) {
        const int i1 = 2 * g, i2 = i1 + 1;
        const float2 a = q2[i1];
        const float2 t = cmulc(q2[i2], tw2);
        q2[i1] = make_float2(a.x + t.x, a.y + t.y);
        q2[i2] = make_float2(a.x - t.x, a.y - t.y);
    }
    // stage s=7: pairs (g*4+c, +2), w = conj(tw1[c])
    #pragma unroll
    for (int g = 0; g < 2; ++g)
        #pragma unroll
        for (int c = 0; c < 2; ++c) {
            const int i1 = g * 4 + c, i2 = i1 + 2;
            const float2 a = q2[i1];
            const float2 t = cmulc(q2[i2], tw1[c]);
            q2[i1] = make_float2(a.x + t.x, a.y + t.y);
            q2[i2] = make_float2(a.x - t.x, a.y - t.y);
        }
    // stage s=8: pairs (c, c+4), w = conj(tw0[c])
    #pragma unroll
    for (int c = 0; c < 4; ++c) {
        const float2 a = q2[c];
        const float2 t = cmulc(q2[c + 4], tw0[c]);
        q2[c]     = make_float2(a.x + t.x, a.y + t.y);
        q2[c + 4] = make_float2(a.x - t.x, a.y - t.y);
    }

    // ---- store: natural order, Re -> row r0, Im -> row r0+1, scale 1/512 ----
    const float scale = 1.0f / (float)NC;
    float* o0 = out + (size_t)r0 * NC;
    float* o1 = o0 + NC;
    #pragma unroll
    for (int it = 0; it < 8; ++it) {
        const int n = it * 64 + lane;
        o0[n] = q2[it].x * scale;
        o1[n] = q2[it].y * scale;
    }
}

extern "C" void kernel_launch(void* const* d_in, const int* in_sizes, int n_in,
                              void* d_out, int out_size, void* d_ws, size_t ws_size,
                              hipStream_t stream) {
    const float* X    = (const float*)d_in[0];
    const int*   idxh = (const int*)d_in[1];
    const int*   bith = (const int*)d_in[2];
    float*       outp = (float*)d_out;

    ushort* ofsq_g = (ushort*)d_ws;                             // 12*513*2 B ~ 12.3 KB
    ushort* ent_g  = (ushort*)((char*)d_ws + ENT_BYTE_OFF);     // 12*1024*2 B = 24 KB

    build_csr<<<DEG * NQ, 512, 0, stream>>>(idxh, bith, ofsq_g, ent_g);

    const int n_rows = in_sizes[0] / F_DIM;            // 8192
    const int blocks = n_rows / 8;                     // 1024 (4 pairs per block)
    ts_kernel<<<blocks, THREADS, 0, stream>>>(X, ofsq_g, ent_g, outp);
}